// Round 10
// baseline (1132.726 us; speedup 1.0000x reference)
//
#include <hip/hip_runtime.h>
#include <math.h>

typedef unsigned long long u64;
typedef unsigned int u32;
typedef unsigned short u16;
typedef _Float16 f16;
typedef __attribute__((ext_vector_type(8))) _Float16 f16x8;
typedef __attribute__((ext_vector_type(8))) unsigned short ushort8;
typedef __attribute__((ext_vector_type(4))) float f32x4;

#define LVTOP 600
#define IMTOP 300
#define NIMG 2
#define NLVL 5
#define NCAND (NLVL*LVTOP)          // 3000

__constant__ int d_HW[5]    = {60800,15200,3800,950,247};
__constant__ int d_LGOFF[5] = {0,364800,456000,478800,484500};
__constant__ int d_RGOFF[5] = {0,1459200,1824000,1915200,1938000};
__constant__ int d_H[5]  = {200,100,50,25,13};
__constant__ int d_W[5]  = {304,152,76,38,19};
__constant__ int d_TX[5] = {7,4,2,1,1};      // 48-wide x-tiles
// xsplit u16 bases per level ([n][cg32][HW][8] chunks)
__constant__ long d_XB[5] = {0, 31129600, 38912000, 40857600, 41344000};
// chunk-count bases (XB/8)
__constant__ long d_CB[5] = {0, 3891200, 4864000, 5107200, 5168000};
#define NCHUNK 5183808
#define NXB 20250                   // xsplit blocks = ceil(NCHUNK/256)
#define WS_NEED 178889200ull

__device__ __forceinline__ u32 okey(float f){
  u32 u = __float_as_uint(f);
  return (u & 0x80000000u) ? ~u : (u | 0x80000000u);
}

// fp16 split-2: v = hi + lo to 22 mantissa bits (residual ~2^-23|v|).
__device__ __forceinline__ void f16_split(float v, u16& hb, u16& lb){
  f16 h = (f16)v;
  float r = v - (float)h;          // exact (Sterbenz)
  f16 l = (f16)r;
  hb = __builtin_bit_cast(u16, h);
  lb = __builtin_bit_cast(u16, l);
}

__device__ __forceinline__ u64 shfl64(u64 v, int src){
  u32 lo = __shfl((u32)v, src);
  u32 hi = __shfl((u32)(v >> 32), src);
  return ((u64)hi << 32) | lo;
}

__device__ __forceinline__ void dma16(const u16* g, u16* l){
  __builtin_amdgcn_global_load_lds(
      (const __attribute__((address_space(1))) u32*)g,
      (__attribute__((address_space(3))) u32*)l, 16, 0, 0);
}

// ---------------- bitonic sorts (block-wide, LDS) ----------------
template<int NN, int NT>
__device__ void bitonic_desc64(u64* a, int tid){
  for (int k = 2; k <= NN; k <<= 1){
    for (int j = k >> 1; j > 0; j >>= 1){
      __syncthreads();
      for (int i = tid; i < NN; i += NT){
        int ixj = i ^ j;
        if (ixj > i){
          u64 x = a[i], y = a[ixj];
          bool up = ((i & k) == 0);
          if (up ? (x < y) : (x > y)){ a[i] = y; a[ixj] = x; }
        }
      }
    }
  }
  __syncthreads();
}

template<int NN, int NT>
__device__ void bitonic_asc32(u32* a, int tid){
  for (int k = 2; k <= NN; k <<= 1){
    for (int j = k >> 1; j > 0; j >>= 1){
      __syncthreads();
      for (int i = tid; i < NN; i += NT){
        int ixj = i ^ j;
        if (ixj > i){
          u32 x = a[i], y = a[ixj];
          bool up = ((i & k) == 0);
          if (up ? (x > y) : (x < y)){ a[i] = y; a[ixj] = x; }
        }
      }
    }
  }
  __syncthreads();
}

// parallel inclusive SUFFIX scan over s[0..NB), NB<=2048, 1024 threads
__device__ void suffix_scan(u32* s, int NB, int tid){
  for (int off = 1; off < NB; off <<= 1){
    u32 v0 = 0, v1 = 0;
    int i1 = tid + 1024;
    if (tid < NB) v0 = s[tid] + ((tid + off < NB) ? s[tid + off] : 0u);
    if (i1  < NB) v1 = s[i1]  + ((i1  + off < NB) ? s[i1  + off] : 0u);
    __syncthreads();
    if (tid < NB) s[tid] = v0;
    if (i1  < NB) s[i1]  = v1;
    __syncthreads();
  }
}

// ---------------- K0: merged prep — xsplit (blocks 0..xsb) + wprep ----------
// wprep's 93 blocks are independent of xsplit (disjoint I/O); merging them
// removes wprep's serial runtime + one launch gap from the critical path.
// wprep sub-blocks 73..92 zero ghist for conv's fused histogram.
__global__ __launch_bounds__(256) void prep(
    const float* __restrict__ f0, const float* __restrict__ f1,
    const float* __restrict__ f2, const float* __restrict__ f3,
    const float* __restrict__ f4,
    u16* __restrict__ xh, u16* __restrict__ xl, u16* __restrict__ zp,
    const float* __restrict__ cw, const float* __restrict__ lw,
    const float* __restrict__ rw, u16* __restrict__ wT, u16* __restrict__ whB,
    u32* __restrict__ ghist, int xsb)
{
  int t = threadIdx.x;
  if ((int)blockIdx.x >= xsb){
    int bid = blockIdx.x - xsb;             // wprep part (93 blocks)
    if (bid < 72){
      int id = bid*256 + t;                 // (tap, co, cc)
      int cc = id & 7;
      int co = (id >> 3) & 255;
      int tap = id >> 11;
      int ntg = co >> 4;
      size_t base = (size_t)((tap*8 + cc)*16 + ntg) * 1024;
      #pragma unroll
      for (int ci = 0; ci < 32; ci++){
        float v = cw[(size_t)co*2304 + (size_t)(cc*32 + ci)*9 + tap];
        u16 hi, lo; f16_split(v, hi, lo);
        int q = ci >> 3, j = ci & 7;
        int lane = q*16 + (co & 15);
        wT[base + lane*8 + j] = hi;
        wT[base + 512 + lane*8 + j] = lo;
      }
    } else if (bid == 72){
      if (t < 128){
        int ks = t >> 4, nn = t & 15;
        for (int ci = 0; ci < 32; ci++){
          int k = ks*32 + ci;
          float v = 0.0f;
          if (nn < 3) v = lw[nn*256 + k];
          else if (nn < 15) v = rw[(nn-3)*256 + k];
          u16 hi, lo; f16_split(v, hi, lo);
          int q = ci >> 3, j = ci & 7;
          int lane = q*16 + nn;
          whB[ks*1024 + lane*8 + j] = hi;
          whB[ks*1024 + 512 + lane*8 + j] = lo;
        }
      }
    } else {
      int z = (bid - 73)*1024 + t;
      #pragma unroll
      for (int q = 0; q < 4; q++){
        int i = z + q*256;
        if (i < NLVL*NIMG*2048) ghist[i] = 0;
      }
    }
    return;
  }
  // xsplit part: chunk id = CB[l] + (n*32+cg)*HW + p ; 8 u16/chunk (ci)
  long id = (long)blockIdx.x*256 + t;
  if (blockIdx.x == 0 && t < 8) zp[t] = 0;  // 16B zero page
  if (id >= NCHUNK) return;
  int l = (id < d_CB[1]) ? 0 : (id < d_CB[2]) ? 1 : (id < d_CB[3]) ? 2 : (id < d_CB[4]) ? 3 : 4;
  long rem = id - d_CB[l];
  int HW = d_HW[l];
  int n = (int)(rem / (32*HW));
  int r2 = (int)(rem - (long)n*32*HW);
  int cg = r2 / HW;
  int p = r2 - cg*HW;
  const float* fm = (l==0)?f0:(l==1)?f1:(l==2)?f2:(l==3)?f3:f4;
  const float* gp = fm + ((size_t)(n*256 + cg*8))*HW + p;
  ushort8 hv, lv;
  #pragma unroll
  for (int j = 0; j < 8; j++){
    float v = gp[(size_t)j*HW];
    u16 hb, lb; f16_split(v, hb, lb);
    hv[j] = hb; lv[j] = lb;
  }
  *(ushort8*)&xh[id*8] = hv;
  *(ushort8*)&xl[id*8] = lv;
}

// ---------------- K1: conv3x3+relu + heads, 48-wide x 2-row tiles -----------
// R6 conv EXACT + fused pass-1 logit histogram (R9, ~neutral but removes a
// dispatch). R7 (256,3)=spill disaster; R8 midhook=-47us — never again.
__global__ __launch_bounds__(256, 2) void conv_mfma(
    const float* __restrict__ f0, const float* __restrict__ f1,
    const float* __restrict__ f2, const float* __restrict__ f3,
    const float* __restrict__ f4,
    const u16* __restrict__ xh, const u16* __restrict__ xl,
    const u16* __restrict__ zp,
    const u16* __restrict__ wT, const u16* __restrict__ whB,
    const float* __restrict__ cb, const float* __restrict__ lb,
    const float* __restrict__ rb,
    float* __restrict__ lgb, float* __restrict__ rgb,
    u32* __restrict__ ghist, int use_dma)
{
  __shared__ __align__(16) u16 smem[26624];  // 53248 B: 2 x (xs_h 6656 + xs_l 6656)

  const int t = threadIdx.x;
  const int n = blockIdx.y;
  int bx = blockIdx.x;
  int l, rbk;
  if (bx < 700){ l = 0; rbk = bx; }
  else if (bx < 900){ l = 1; rbk = bx - 700; }
  else if (bx < 950){ l = 2; rbk = bx - 900; }
  else if (bx < 963){ l = 3; rbk = bx - 950; }
  else { l = 4; rbk = bx - 963; }
  const int H = d_H[l], W = d_W[l], tilesX = d_TX[l];
  const int ty2 = rbk / tilesX;                 // row-pair index
  const int x0 = (rbk - ty2*tilesX) * 48;
  const float* fm = (l==0) ? f0 : (l==1) ? f1 : (l==2) ? f2 : (l==3) ? f3 : f4;

  const int wave = t >> 6, lane = t & 63;
  const int quad = lane >> 4, l15 = lane & 15;
  const int HWp = H * W;
  const float* xin = fm + (size_t)n * 256 * HWp;

  f32x4 acc[2][3][4];
  #pragma unroll
  for (int r = 0; r < 2; r++)
    #pragma unroll
    for (int a = 0; a < 3; a++)
      #pragma unroll
      for (int b = 0; b < 4; b++) acc[r][a][b] = (f32x4){0.f,0.f,0.f,0.f};

  // MFMA tap loop: per tap, batch-load 4 B pairs, then 2 rows x 4 nt x 3 mt.
  // LDS A layout: [cg4][row4][xi52][8ci] (linear chunk index g*8).
  auto compute_cc = [&](int cc, int bufo){
    #pragma unroll
    for (int ky = 0; ky < 3; ky++){
      #pragma unroll
      for (int kx = 0; kx < 3; kx++){
        const u16* bt = wT + (size_t)((((ky*3+kx)*8 + cc)*16) + wave*4) * 1024 + lane*8;
        f16x8 Bh[4], Bl[4];
        #pragma unroll
        for (int nt = 0; nt < 4; nt++){
          Bh[nt] = *(const f16x8*)(bt + nt*1024);
          Bl[nt] = *(const f16x8*)(bt + nt*1024 + 512);
        }
        #pragma unroll
        for (int row = 0; row < 2; row++){
          int o0 = bufo + ((quad*4 + ky + row)*52 + (l15 + kx))*8;
          f16x8 Ah[3], Al[3];
          #pragma unroll
          for (int mt = 0; mt < 3; mt++){
            Ah[mt] = *(const f16x8*)&smem[o0 + mt*128];
            Al[mt] = *(const f16x8*)&smem[o0 + 6656 + mt*128];
          }
          #pragma unroll
          for (int nt = 0; nt < 4; nt++){
            #pragma unroll
            for (int mt = 0; mt < 3; mt++){
              acc[row][mt][nt] = __builtin_amdgcn_mfma_f32_16x16x32_f16(Ah[mt], Bh[nt], acc[row][mt][nt], 0,0,0);
              acc[row][mt][nt] = __builtin_amdgcn_mfma_f32_16x16x32_f16(Al[mt], Bh[nt], acc[row][mt][nt], 0,0,0);
              acc[row][mt][nt] = __builtin_amdgcn_mfma_f32_16x16x32_f16(Ah[mt], Bl[nt], acc[row][mt][nt], 0,0,0);
            }
          }
        }
      }
    }
  };

  if (use_dma){
    // per-slot DMA descriptors: wave issues slots k = wave + 4s (13 slots, exact)
    const u16* ph[4]; const u16* pl[4]; u32 pstep[4]; int dsth[4]; int kv[4];
    #pragma unroll
    for (int s = 0; s < 4; s++){
      int k = wave + s*4;
      kv[s] = (k < 13);
      int kk = kv[s] ? k : 0;
      int g = kk*64 + lane;              // chunk 0..831 (all real, 13x64=832)
      int cg = g / 208; int rem = g - cg*208;
      int r = rem / 52;  int xi = rem - r*52;
      int gy = ty2*2 - 1 + r, gx = x0 - 1 + xi;
      bool inb = (gy >= 0) && (gy < H) && (gx >= 0) && (gx < W);
      int gy2 = gy < 0 ? 0 : (gy >= H ? H-1 : gy);
      int gx2 = gx < 0 ? 0 : (gx >= W ? W-1 : gx);
      long off = d_XB[l] + (((long)(n*32 + cg))*HWp + (long)gy2*W + gx2)*8;
      ph[s] = inb ? (xh + off) : zp;
      pl[s] = inb ? (xl + off) : zp;
      pstep[s] = inb ? (u32)(32*HWp) : 0u;   // next cc: +4 channel-groups
      dsth[s] = kk*512;                      // u16 offset (k*1024 B)
    }
    auto stage = [&](int bufo){
      #pragma unroll
      for (int s = 0; s < 4; s++){
        if (kv[s]){
          dma16(ph[s], &smem[bufo + dsth[s]]);
          dma16(pl[s], &smem[bufo + 6656 + dsth[s]]);
          ph[s] += pstep[s]; pl[s] += pstep[s];
        }
      }
    };
    stage(0);
    __syncthreads();                        // drains DMA for cc=0
    for (int cc = 0; cc < 8; cc++){
      if (cc < 7) stage(((cc+1)&1)*13312);  // in flight during compute
      compute_cc(cc, (cc&1)*13312);
      __syncthreads();                      // drains next DMA + protects buf reuse
    }
  } else {
    // fallback (small ws): f32 staging + in-register split, single buffer
    for (int cc = 0; cc < 8; cc++){
      __syncthreads();
      #pragma unroll
      for (int it = 0; it < 4; it++){
        int G = t + it*256;
        if (G < 832){
          int cg = G / 208; int rem = G - cg*208;
          int r = rem / 52; int xi = rem - r*52;
          int gy = ty2*2 - 1 + r, gx = x0 - 1 + xi;
          bool inb = (gy >= 0) & (gy < H) & (gx >= 0) & (gx < W);
          const float* gp = xin + (size_t)(cc*32 + cg*8) * HWp
                          + (size_t)(gy < 0 ? 0 : gy) * W + (gx < 0 ? 0 : gx);
          ushort8 hv, lv;
          #pragma unroll
          for (int j = 0; j < 8; j++){
            float v = inb ? gp[(size_t)j * HWp] : 0.0f;
            u16 hb, lb2; f16_split(v, hb, lb2);
            hv[j] = hb; lv[j] = lb2;
          }
          int off = G*8;
          *(ushort8*)&smem[off] = hv;
          *(ushort8*)&smem[6656 + off] = lv;
        }
      }
      __syncthreads();
      compute_cc(cc, 0);
    }
    __syncthreads();
  }

  // fused pass-1 logit histogram: LDS bytes 34816..43008 — disjoint from
  // heads' hA_h/hA_l and sm_out; staging buffers dead after final cc barrier.
  u32* lhist = (u32*)(smem + 17408);
  for (int i = t; i < 2048; i += 256) lhist[i] = 0;

  // ---- heads per output row (unrolled, static acc index) ----
  u16* hA_h = smem;                // [64 pos][136]; rows 48..63 unused garbage
  u16* hA_l = smem + 8704;
  #pragma unroll
  for (int row = 0; row < 2; row++){
    const int ty = ty2*2 + row;
    const bool rowok = (ty < H);           // uniform per block
    if (rowok){
      f32x4 a2 = (f32x4){0.f,0.f,0.f,0.f};
      #pragma unroll
      for (int half = 0; half < 2; half++){
        if ((wave >> 1) == half){
          #pragma unroll
          for (int mt = 0; mt < 3; mt++){
            #pragma unroll
            for (int nt = 0; nt < 4; nt++){
              int col = (wave & 1)*64 + nt*16 + l15;   // local 0..127 in half
              float bias = cb[half*128 + col];
              #pragma unroll
              for (int r = 0; r < 4; r++){
                float h = fmaxf(acc[row][mt][nt][r] + bias, 0.0f);
                u16 hb, lb2; f16_split(h, hb, lb2);
                int pos = mt*16 + quad*4 + r;          // 0..47
                hA_h[pos*136 + col] = hb;
                hA_l[pos*136 + col] = lb2;
              }
            }
          }
        }
        __syncthreads();
        #pragma unroll
        for (int ks2 = 0; ks2 < 4; ks2++){
          int ks = half*4 + ks2;
          int ao = (wave*16 + l15)*136 + ks2*32 + quad*8;  // wave3: garbage rows
          f16x8 Ah = *(const f16x8*)&hA_h[ao];
          f16x8 Al = *(const f16x8*)&hA_l[ao];
          const u16* wb = whB + ks*1024 + lane*8;
          f16x8 Bh = *(const f16x8*)wb;
          f16x8 Bl = *(const f16x8*)(wb + 512);
          a2 = __builtin_amdgcn_mfma_f32_16x16x32_f16(Ah, Bh, a2, 0,0,0);
          a2 = __builtin_amdgcn_mfma_f32_16x16x32_f16(Al, Bh, a2, 0,0,0);
          a2 = __builtin_amdgcn_mfma_f32_16x16x32_f16(Ah, Bl, a2, 0,0,0);
        }
        __syncthreads();
      }

      // coalesced epilogue through LDS (rows 48..63 of sm_out never read)
      float* sm_out = (float*)smem;        // [64 pos][16]
      {
        int o = l15;
        float bias = (o < 3) ? lb[o] : ((o < 15) ? rb[o-3] : 0.0f);
        #pragma unroll
        for (int r = 0; r < 4; r++){
          int pos = wave*16 + quad*4 + r;
          sm_out[pos*16 + o] = a2[r] + bias;
        }
      }
      __syncthreads();
      {
        int P = W - x0; if (P > 48) P = 48;
        size_t pbase = (size_t)ty * W + x0;
        float* lg = lgb + d_LGOFF[l] + (size_t)n*HWp*3  + pbase*3;
        float* rg = rgb + d_RGOFF[l] + (size_t)n*HWp*12 + pbase*12;
        for (int j = t; j < P*3; j += 256){
          float v = sm_out[(j/3)*16 + (j%3)];
          lg[j] = v;
          atomicAdd(&lhist[okey(v) >> 21], 1u);
        }
        for (int j = t; j < P*12; j += 256) rg[j] = sm_out[(j/12)*16 + 3 + (j%12)];
      }
      __syncthreads();                     // before next row reuses smem
    }
  }

  // merge block-local histogram into the (l,n) global histogram
  {
    u32* gh = ghist + (size_t)(l*NIMG + n) * 2048;
    for (int i = t; i < 2048; i += 256){
      u32 h = lhist[i];
      if (h) atomicAdd(&gh[i], h);
    }
  }
}

// ---------------- K2: exact per-level top-600 + decode + clip ----------------
__global__ __launch_bounds__(1024) void topk_decode(
    const float* __restrict__ lg, const float* __restrict__ rg,
    const float* __restrict__ pr0, const float* __restrict__ pr1,
    const float* __restrict__ pr2, const float* __restrict__ pr3,
    const float* __restrict__ pr4,
    const float* __restrict__ imsizes, const u32* __restrict__ ghist,
    float* __restrict__ cbox, float* __restrict__ cscore, u32* __restrict__ cvalid)
{
  __shared__ u32 hist[2048];
  __shared__ u32 sscan[2048];
  __shared__ u64 sel[1024];
  __shared__ u32 eqbuf[1024];
  __shared__ u32 scal[8];
  int tid = threadIdx.x;
  int l = blockIdx.x / NIMG;
  int n = blockIdx.x - l*NIMG;
  int HW = d_HW[l];
  int N = HW * 3;
  const float* lgl = lg + d_LGOFF[l] + (size_t)n * N;

  // pass 1: bits [31:21] — precomputed by conv_mfma's fused histogram
  {
    const u32* gh = ghist + (size_t)blockIdx.x * 2048;
    for (int i = tid; i < 2048; i += 1024){ u32 h = gh[i]; hist[i] = h; sscan[i] = h; }
  }
  __syncthreads();
  suffix_scan(sscan, 2048, tid);
  if (tid < 2048){
    u32 Si = sscan[tid], Sn = (tid+1 < 2048) ? sscan[tid+1] : 0u;
    if (Si >= LVTOP && Sn < LVTOP){ scal[0] = (u32)tid; scal[1] = Si - hist[tid]; }
  }
  { int i2 = tid + 1024;
    u32 Si = sscan[i2], Sn = (i2+1 < 2048) ? sscan[i2+1] : 0u;
    if (Si >= LVTOP && Sn < LVTOP){ scal[0] = (u32)i2; scal[1] = Si - hist[i2]; } }
  __syncthreads();
  u32 B1 = scal[0], base1 = scal[1];

  // pass 2: bits [20:10] within B1
  for (int i = tid; i < 2048; i += 1024) hist[i] = 0;
  __syncthreads();
  for (int i = tid; i < N; i += 1024){
    u32 k = okey(lgl[i]);
    if ((k >> 21) == B1) atomicAdd(&hist[(k >> 10) & 0x7FFu], 1u);
  }
  __syncthreads();
  for (int i = tid; i < 2048; i += 1024) sscan[i] = hist[i];
  __syncthreads();
  suffix_scan(sscan, 2048, tid);
  {
    u32 need = LVTOP - base1;
    if (tid < 2048){
      u32 Si = sscan[tid], Sn = (tid+1 < 2048) ? sscan[tid+1] : 0u;
      if (Si >= need && Sn < need){ scal[2] = (u32)tid; scal[3] = base1 + Si - hist[tid]; }
    }
    int i2 = tid + 1024;
    u32 Si = sscan[i2], Sn = (i2+1 < 2048) ? sscan[i2+1] : 0u;
    if (Si >= need && Sn < need){ scal[2] = (u32)i2; scal[3] = base1 + Si - hist[i2]; }
  }
  __syncthreads();
  u32 B2 = scal[2], base2 = scal[3];

  // pass 3: bits [9:0] within (B1,B2)
  for (int i = tid; i < 1024; i += 1024) hist[i] = 0;
  __syncthreads();
  u32 hi21 = (B1 << 11) | B2;
  for (int i = tid; i < N; i += 1024){
    u32 k = okey(lgl[i]);
    if ((k >> 10) == hi21) atomicAdd(&hist[k & 0x3FFu], 1u);
  }
  __syncthreads();
  for (int i = tid; i < 1024; i += 1024) sscan[i] = hist[i];
  __syncthreads();
  suffix_scan(sscan, 1024, tid);
  {
    u32 need = LVTOP - base2;
    if (tid < 1024){
      u32 Si = sscan[tid], Sn = (tid+1 < 1024) ? sscan[tid+1] : 0u;
      if (Si >= need && Sn < need){
        scal[4] = (hi21 << 10) | (u32)tid;
        scal[5] = base2 + Si - hist[tid];
      }
    }
  }
  if (tid == 0){ scal[6] = 0; scal[7] = 0; }
  __syncthreads();
  u32 T = scal[4], nAbove = scal[5], needEq = LVTOP - scal[5];

  for (int i = tid; i < 1024; i += 1024) sel[i] = 0;
  __syncthreads();
  for (int i = tid; i < N; i += 1024){
    u32 k = okey(lgl[i]);
    if (k > T){
      u32 p = atomicAdd(&scal[6], 1u);
      sel[p] = ((u64)k << 32) | (0xFFFFFFFFu - (u32)i);
    } else if (k == T){
      u32 p = atomicAdd(&scal[7], 1u);
      if (p < 1024) eqbuf[p] = (u32)i;
    }
  }
  __syncthreads();
  u32 cntE = scal[7];
  if (cntE > needEq){               // lowest-index ties (lax.top_k semantics)
    u32 m = cntE < 1024u ? cntE : 1024u;
    for (int i = tid; i < 1024; i += 1024) if ((u32)i >= m) eqbuf[i] = 0xFFFFFFFFu;
    __syncthreads();
    bitonic_asc32<1024,1024>(eqbuf, tid);
  }
  __syncthreads();
  if ((u32)tid < needEq)
    sel[nAbove + tid] = ((u64)T << 32) | (0xFFFFFFFFu - eqbuf[tid]);
  __syncthreads();
  // rank-by-count placement (replaces 55-stage bitonic): the 600 real
  // composite keys are distinct -> ranks 0..599 unique; the 424 zeros all
  // rank 600 and write identical 0 (benign). Decode reads tid<600 only.
  {
    u64 mykey = sel[tid];
    int rank = 0;
    for (int j = 0; j < 1024; j++) rank += (sel[j] > mykey) ? 1 : 0;
    __syncthreads();
    sel[rank] = mykey;
  }
  __syncthreads();

  // decode + clip + validity
  if (tid < LVTOP){
    u64 c = sel[tid];
    u32 i = 0xFFFFFFFFu - (u32)c;
    float val = lgl[i];
    float score = 1.0f / (1.0f + expf(-val));
    int pp = (int)i / 3, a = (int)i - pp*3;
    const float* pri;
    if (l == 0) pri = pr0; else if (l == 1) pri = pr1; else if (l == 2) pri = pr2;
    else if (l == 3) pri = pr3; else pri = pr4;
    pri += (size_t)i * 4;
    const float* rgp = rg + d_RGOFF[l] + ((size_t)n * HW + pp) * 12 + a * 4;
    float px0 = pri[0], py0 = pri[1], px1 = pri[2], py1 = pri[3];
    float pw = px1 - px0, ph = py1 - py0;
    float pcx = px0 + 0.5f*pw, pcy = py0 + 0.5f*ph;
    const float BC = (float)4.135166556742356;   // log(1000/16)
    float dx = rgp[0], dy = rgp[1];
    float dw = fminf(rgp[2], BC), dh = fminf(rgp[3], BC);
    float cx = dx*pw + pcx, cy = dy*ph + pcy;
    float bw = pw * expf(dw), bh = ph * expf(dh);
    float x1 = cx - 0.5f*bw, y1 = cy - 0.5f*bh;
    float x2 = cx + 0.5f*bw, y2 = cy + 0.5f*bh;
    float imh = imsizes[n*2+0], imw = imsizes[n*2+1];
    x1 = fminf(fmaxf(x1, 0.0f), imw);
    y1 = fminf(fmaxf(y1, 0.0f), imh);
    x2 = fminf(fmaxf(x2, 0.0f), imw);
    y2 = fminf(fmaxf(y2, 0.0f), imh);
    u32 valid = (score >= 0.0f) && ((x2 - x1) >= 1e-2f) && ((y2 - y1) >= 1e-2f);
    int ci = n*NCAND + l*LVTOP + tid;
    cbox[ci*4+0] = x1; cbox[ci*4+1] = y1; cbox[ci*4+2] = x2; cbox[ci*4+3] = y2;
    cscore[ci] = score; cvalid[ci] = valid;
  }
}

// ---------------- K3: per-image stable sort + per-level rank lists ----------
__global__ __launch_bounds__(1024) void sort_cand(
    const float* __restrict__ cscore, const u32* __restrict__ cvalid,
    const float* __restrict__ cbox,
    float* __restrict__ sbox, float* __restrict__ sob,
    float* __restrict__ sarea, u32* __restrict__ svalid,
    u32* __restrict__ rlist, u32* __restrict__ kflag)
{
  __shared__ u64 a[4096];
  int tid = threadIdx.x, n = blockIdx.x;
  for (int i = tid; i < 4096; i += 1024){
    if (i < NCAND){
      int ci = n*NCAND + i;
      float s = cvalid[ci] ? cscore[ci] : -1.0f;   // ref: where(valid, obj, -1)
      a[i] = ((u64)okey(s) << 32) | (0xFFFFFFFFu - (u32)i);
    } else a[i] = 0;
  }
  bitonic_desc64<4096,1024>(a, tid);
  int mylvl[3];
  #pragma unroll
  for (int q = 0; q < 3; q++){
    int r = tid + q*1024;
    mylvl[q] = 0;
    if (r < NCAND){
      u32 li = 0xFFFFFFFFu - (u32)a[r];
      int ci = n*NCAND + (int)li;
      float b0 = cbox[ci*4+0], b1 = cbox[ci*4+1], b2 = cbox[ci*4+2], b3 = cbox[ci*4+3];
      int lvl = (int)li / LVTOP;
      mylvl[q] = lvl;
      float off = (float)(n*10 + lvl) * 4096.0f;   // fp32 batched_nms offset
      int so = n*NCAND + r;
      sbox[so*4+0]=b0; sbox[so*4+1]=b1; sbox[so*4+2]=b2; sbox[so*4+3]=b3;
      float o0=b0+off, o1=b1+off, o2=b2+off, o3=b3+off;
      sob[so*4+0]=o0; sob[so*4+1]=o1; sob[so*4+2]=o2; sob[so*4+3]=o3;
      sarea[so] = (o2-o0)*(o3-o1);
      svalid[so] = cvalid[ci];
    }
  }
  __syncthreads();
  // per-level stable position via one u64 multi-field inclusive scan
  #pragma unroll
  for (int q = 0; q < 3; q++){
    int r = tid + q*1024;
    a[r] = (r < NCAND) ? (1ull << (12*mylvl[q])) : 0ull;
  }
  a[tid + 3072] = 0ull;
  __syncthreads();
  for (int off = 1; off < 4096; off <<= 1){
    u64 v[4];
    #pragma unroll
    for (int q = 0; q < 4; q++){
      int i = tid + q*1024;
      v[q] = a[i] + ((i >= off) ? a[i-off] : 0ull);
    }
    __syncthreads();
    #pragma unroll
    for (int q = 0; q < 4; q++) a[tid + q*1024] = v[q];
    __syncthreads();
  }
  #pragma unroll
  for (int q = 0; q < 3; q++){
    int r = tid + q*1024;
    if (r < NCAND){
      int lv = mylvl[q];
      int pos = (int)((a[r] >> (12*lv)) & 0xFFFull) - 1;
      rlist[(n*NLVL + lv)*LVTOP + pos] = (u32)r;
      kflag[n*NCAND + r] = 0u;
    }
  }
}

// ---------------- K4: fused per-level NMS — masks in LDS + greedy scan ------
// One block per (n,l): stage the 600 rlist-ordered boxes in LDS, compute the
// 600x600/64 mask words directly into LDS (no pmask global round-trip), then
// wave0 runs the word-skip greedy scan. LDS: 12000 (boxes) + 48000 (masks)
// = 60000 B < 64 KB static limit.
__global__ __launch_bounds__(256) void nms_l(
    const float* __restrict__ sob, const float* __restrict__ sarea,
    const u32* __restrict__ svalid, const u32* __restrict__ rlist,
    u32* __restrict__ kflag)
{
  __shared__ float bx[LVTOP*5];     // 12000 B
  __shared__ u64 pm[LVTOP*10];      // 48000 B
  int t = threadIdx.x, nl = blockIdx.x, n = nl / NLVL;
  // stage boxes in rlist order
  for (int i = t; i < LVTOP; i += 256){
    int so = n*NCAND + (int)rlist[nl*LVTOP + i];
    bx[i*5+0]=sob[so*4+0]; bx[i*5+1]=sob[so*4+1];
    bx[i*5+2]=sob[so*4+2]; bx[i*5+3]=sob[so*4+3];
    bx[i*5+4]=sarea[so];
  }
  __syncthreads();
  // mask build: each thread owns rows i = t, t+256, ...
  for (int i = t; i < LVTOP; i += 256){
    int so = n*NCAND + (int)rlist[nl*LVTOP + i];
    bool act = svalid[so] != 0;
    float oi0=bx[i*5+0], oi1=bx[i*5+1], oi2=bx[i*5+2], oi3=bx[i*5+3], ai=bx[i*5+4];
    for (int w = 0; w < 10; w++){
      u64 bits = 0;
      if (act){
        int jj0 = (i >= w*64) ? (i - w*64 + 1) : 0;
        int jjend = (LVTOP - w*64 < 64) ? (LVTOP - w*64) : 64;
        for (int jj = jj0; jj < jjend; jj++){
          int j = w*64 + jj;
          float oj0=bx[j*5+0], oj1=bx[j*5+1], oj2=bx[j*5+2], oj3=bx[j*5+3], aj=bx[j*5+4];
          float ltx = fmaxf(oi0, oj0), lty = fmaxf(oi1, oj1);
          float rbx = fminf(oi2, oj2), rby = fminf(oi3, oj3);
          float wx = fmaxf(rbx - ltx, 0.0f), wy = fmaxf(rby - lty, 0.0f);
          float inter = wx * wy;
          float iou = inter / ((ai + aj) - inter);
          if (iou > 0.7f) bits |= (1ull << jj);
        }
      }
      pm[i*10 + w] = bits;
    }
  }
  __syncthreads();
  if (t < 64){
    u64 vw = 0, remv = 0;
    for (int c = 0; c < 10; c++){
      int i = c*64 + t;
      int pred = 0;
      if (i < LVTOP) pred = svalid[n*NCAND + (int)rlist[nl*LVTOP + i]] != 0;
      u64 b = __ballot(pred);
      if (t == c) vw = b;
    }
    for (int w = 0; w < 10; w++){
      u64 act = shfl64(vw, w) & ~shfl64(remv, w);
      while (act){
        int bpos = __builtin_ctzll(act);
        int i = w*64 + bpos;
        if (t == 0) kflag[n*NCAND + (int)rlist[nl*LVTOP + i]] = 1u;
        u64 m = (t < 10) ? pm[i*10 + t] : 0ull;
        u64 mw = pm[i*10 + w];         // broadcast (same addr all lanes)
        remv |= m;
        act &= ~(1ull << bpos);
        act &= ~mw;
      }
    }
  }
}

// ---------------- K6: prefix-sum cap-300 merge + output ---------------------
__global__ __launch_bounds__(1024) void merge_out(
    const u32* __restrict__ kflag, const float* __restrict__ sbox,
    float* __restrict__ out)
{
  __shared__ u32 ps[4096];
  int tid = threadIdx.x, n = blockIdx.x;
  u32 f[4];
  #pragma unroll
  for (int q = 0; q < 4; q++){
    int i = tid + q*1024;
    f[q] = (i < NCAND) ? kflag[n*NCAND + i] : 0u;
    ps[i] = f[q];
  }
  __syncthreads();
  for (int off = 1; off < 4096; off <<= 1){
    u32 v[4];
    #pragma unroll
    for (int q = 0; q < 4; q++){
      int i = tid + q*1024;
      v[q] = ps[i] + ((i >= off) ? ps[i-off] : 0u);
    }
    __syncthreads();
    #pragma unroll
    for (int q = 0; q < 4; q++) ps[tid + q*1024] = v[q];
    __syncthreads();
  }
  #pragma unroll
  for (int q = 0; q < 4; q++){
    int i = tid + q*1024;
    if (i < NCAND && f[q] && ps[i] <= IMTOP){
      int slot = n*IMTOP + (int)ps[i] - 1;
      int so = n*NCAND + i;
      out[slot*4+0] = sbox[so*4+0]; out[slot*4+1] = sbox[so*4+1];
      out[slot*4+2] = sbox[so*4+2]; out[slot*4+3] = sbox[so*4+3];
    }
  }
  u32 kept = ps[NCAND-1]; if (kept > IMTOP) kept = IMTOP;
  for (int j = tid; j < IMTOP; j += 1024){
    int slot = n*IMTOP + j;
    if ((u32)j >= kept){
      out[slot*4+0]=0; out[slot*4+1]=0; out[slot*4+2]=0; out[slot*4+3]=0;
    }
    out[2400 + slot] = (float)n;
    out[3000 + slot] = ((u32)j < kept) ? 1.0f : 0.0f;
  }
}

extern "C" void kernel_launch(void* const* d_in, const int* in_sizes, int n_in,
                              void* d_out, int out_size, void* d_ws, size_t ws_size,
                              hipStream_t stream)
{
  const float* fmap[5]   = {(const float*)d_in[0], (const float*)d_in[2], (const float*)d_in[4],
                            (const float*)d_in[6], (const float*)d_in[8]};
  const float* priors[5] = {(const float*)d_in[1], (const float*)d_in[3], (const float*)d_in[5],
                            (const float*)d_in[7], (const float*)d_in[9]};
  const float* imsz   = (const float*)d_in[10];
  const float* conv_w = (const float*)d_in[11];
  const float* conv_b = (const float*)d_in[12];
  const float* log_w  = (const float*)d_in[13];
  const float* log_b  = (const float*)d_in[14];
  const float* reg_w  = (const float*)d_in[15];
  const float* reg_b  = (const float*)d_in[16];

  char* base = (char*)d_ws;
  float* lg     = (float*)(base + 0);          // 1943928 B
  float* rg     = (float*)(base + 1943928);    // 7775712 B
  float* cscore = (float*)(base + 9719640);
  float* cbox   = (float*)(base + 9743640);
  u32*   cvalid = (u32*)  (base + 9839640);
  float* sbox   = (float*)(base + 9863640);
  float* sob    = (float*)(base + 9959640);
  float* sarea  = (float*)(base + 10055640);
  u32*   svalid = (u32*)  (base + 10079640);
  u32*   rlist  = (u32*)  (base + 10103640);   // 24000 B
  u32*   kflag  = (u32*)  (base + 10127640);   // 24000 B
  u32*   ghist  = (u32*)  (base + 10151648);   // 81920 B (10 x 2048 u32)
  u16*   wT     = (u16*)  (base + 10631648);   // 2359296 B
  u16*   whB    = (u16*)  (base + 12990944);   // 16384 B
  u16*   zp     = (u16*)  (base + 13007328);   // 16 B zero page
  u16*   xh     = (u16*)  (base + 13007344);   // 82940928 B
  u16*   xl     = (u16*)  (base + 95948272);   // 82940928 B -> 178889200

  int use_dma = (ws_size >= WS_NEED) ? 1 : 0;
  int xsb = use_dma ? NXB : 0;

  prep<<<xsb + 93, 256, 0, stream>>>(
      fmap[0], fmap[1], fmap[2], fmap[3], fmap[4], xh, xl, zp,
      conv_w, log_w, reg_w, wT, whB, ghist, xsb);

  conv_mfma<<<dim3(970, NIMG), 256, 0, stream>>>(
      fmap[0], fmap[1], fmap[2], fmap[3], fmap[4],
      xh, xl, zp, wT, whB, conv_b, log_b, reg_b, lg, rg, ghist, use_dma);

  topk_decode<<<NLVL*NIMG, 1024, 0, stream>>>(lg, rg,
      priors[0], priors[1], priors[2], priors[3], priors[4],
      imsz, ghist, cbox, cscore, cvalid);
  sort_cand<<<NIMG, 1024, 0, stream>>>(cscore, cvalid, cbox, sbox, sob, sarea,
                                       svalid, rlist, kflag);
  nms_l<<<NIMG*NLVL, 256, 0, stream>>>(sob, sarea, svalid, rlist, kflag);
  merge_out<<<NIMG, 1024, 0, stream>>>(kflag, sbox, (float*)d_out);
}

// Round 11
// 1114.602 us; speedup vs baseline: 1.0163x; 1.0163x over previous
//
#include <hip/hip_runtime.h>
#include <math.h>

typedef unsigned long long u64;
typedef unsigned int u32;
typedef unsigned short u16;
typedef _Float16 f16;
typedef __attribute__((ext_vector_type(8))) _Float16 f16x8;
typedef __attribute__((ext_vector_type(8))) unsigned short ushort8;
typedef __attribute__((ext_vector_type(4))) float f32x4;

#define LVTOP 600
#define IMTOP 300
#define NIMG 2
#define NLVL 5
#define NCAND (NLVL*LVTOP)          // 3000
#define FNB (NIMG*NLVL)             // 10 post-blocks

__constant__ int d_HW[5]    = {60800,15200,3800,950,247};
__constant__ int d_LGOFF[5] = {0,364800,456000,478800,484500};
__constant__ int d_RGOFF[5] = {0,1459200,1824000,1915200,1938000};
__constant__ int d_H[5]  = {200,100,50,25,13};
__constant__ int d_W[5]  = {304,152,76,38,19};
__constant__ int d_TX[5] = {7,4,2,1,1};      // 48-wide x-tiles
// xsplit u16 bases per level ([n][cg32][HW][8] chunks)
__constant__ long d_XB[5] = {0, 31129600, 38912000, 40857600, 41344000};
// chunk-count bases (XB/8)
__constant__ long d_CB[5] = {0, 3891200, 4864000, 5107200, 5168000};
#define NCHUNK 5183808
#define NXB 20250                   // xsplit blocks = ceil(NCHUNK/256)
#define WS_NEED 178889200ull

__device__ __forceinline__ u32 okey(float f){
  u32 u = __float_as_uint(f);
  return (u & 0x80000000u) ? ~u : (u | 0x80000000u);
}

// fp16 split-2: v = hi + lo to 22 mantissa bits (residual ~2^-23|v|).
__device__ __forceinline__ void f16_split(float v, u16& hb, u16& lb){
  f16 h = (f16)v;
  float r = v - (float)h;          // exact (Sterbenz)
  f16 l = (f16)r;
  hb = __builtin_bit_cast(u16, h);
  lb = __builtin_bit_cast(u16, l);
}

__device__ __forceinline__ u64 shfl64(u64 v, int src){
  u32 lo = __shfl((u32)v, src);
  u32 hi = __shfl((u32)(v >> 32), src);
  return ((u64)hi << 32) | lo;
}

__device__ __forceinline__ void dma16(const u16* g, u16* l){
  __builtin_amdgcn_global_load_lds(
      (const __attribute__((address_space(1))) u32*)g,
      (__attribute__((address_space(3))) u32*)l, 16, 0, 0);
}

// grid barrier for the 10-block post kernel: cumulative device-scope counter.
// Co-residency is guaranteed (10 blocks, 1 block/CU by LDS, 256 CUs idle).
__device__ __forceinline__ void gsync(u32* bar, u32 target){
  __threadfence();                 // release this thread's prior writes
  __syncthreads();
  if (threadIdx.x == 0){
    atomicAdd(bar, 1u);
    while (atomicAdd(bar, 0u) < target){ }
  }
  __syncthreads();
  __threadfence();                 // acquire other blocks' writes
}

// ---------------- bitonic sorts (block-wide, LDS) ----------------
template<int NN, int NT>
__device__ void bitonic_desc64(u64* a, int tid){
  for (int k = 2; k <= NN; k <<= 1){
    for (int j = k >> 1; j > 0; j >>= 1){
      __syncthreads();
      for (int i = tid; i < NN; i += NT){
        int ixj = i ^ j;
        if (ixj > i){
          u64 x = a[i], y = a[ixj];
          bool up = ((i & k) == 0);
          if (up ? (x < y) : (x > y)){ a[i] = y; a[ixj] = x; }
        }
      }
    }
  }
  __syncthreads();
}

template<int NN, int NT>
__device__ void bitonic_asc32(u32* a, int tid){
  for (int k = 2; k <= NN; k <<= 1){
    for (int j = k >> 1; j > 0; j >>= 1){
      __syncthreads();
      for (int i = tid; i < NN; i += NT){
        int ixj = i ^ j;
        if (ixj > i){
          u32 x = a[i], y = a[ixj];
          bool up = ((i & k) == 0);
          if (up ? (x > y) : (x < y)){ a[i] = y; a[ixj] = x; }
        }
      }
    }
  }
  __syncthreads();
}

// parallel inclusive SUFFIX scan over s[0..NB), NB<=2048, 1024 threads
__device__ void suffix_scan(u32* s, int NB, int tid){
  for (int off = 1; off < NB; off <<= 1){
    u32 v0 = 0, v1 = 0;
    int i1 = tid + 1024;
    if (tid < NB) v0 = s[tid] + ((tid + off < NB) ? s[tid + off] : 0u);
    if (i1  < NB) v1 = s[i1]  + ((i1  + off < NB) ? s[i1  + off] : 0u);
    __syncthreads();
    if (tid < NB) s[tid] = v0;
    if (i1  < NB) s[i1]  = v1;
    __syncthreads();
  }
}

// ---------------- K0: merged prep — xsplit (blocks 0..xsb) + wprep ----------
// wprep blocks run LAST: wT/whB land hot in L2 right before conv's B-loads
// (accidental R10 discovery: conv 512->483us from this ordering).
// wprep sub-blocks 73..92 zero ghist; block 73 also zeroes the grid barrier.
__global__ __launch_bounds__(256) void prep(
    const float* __restrict__ f0, const float* __restrict__ f1,
    const float* __restrict__ f2, const float* __restrict__ f3,
    const float* __restrict__ f4,
    u16* __restrict__ xh, u16* __restrict__ xl, u16* __restrict__ zp,
    const float* __restrict__ cw, const float* __restrict__ lw,
    const float* __restrict__ rw, u16* __restrict__ wT, u16* __restrict__ whB,
    u32* __restrict__ ghist, u32* __restrict__ bar, int xsb)
{
  int t = threadIdx.x;
  if ((int)blockIdx.x >= xsb){
    int bid = blockIdx.x - xsb;             // wprep part (93 blocks)
    if (bid < 72){
      int id = bid*256 + t;                 // (tap, co, cc)
      int cc = id & 7;
      int co = (id >> 3) & 255;
      int tap = id >> 11;
      int ntg = co >> 4;
      size_t base = (size_t)((tap*8 + cc)*16 + ntg) * 1024;
      #pragma unroll
      for (int ci = 0; ci < 32; ci++){
        float v = cw[(size_t)co*2304 + (size_t)(cc*32 + ci)*9 + tap];
        u16 hi, lo; f16_split(v, hi, lo);
        int q = ci >> 3, j = ci & 7;
        int lane = q*16 + (co & 15);
        wT[base + lane*8 + j] = hi;
        wT[base + 512 + lane*8 + j] = lo;
      }
    } else if (bid == 72){
      if (t < 128){
        int ks = t >> 4, nn = t & 15;
        for (int ci = 0; ci < 32; ci++){
          int k = ks*32 + ci;
          float v = 0.0f;
          if (nn < 3) v = lw[nn*256 + k];
          else if (nn < 15) v = rw[(nn-3)*256 + k];
          u16 hi, lo; f16_split(v, hi, lo);
          int q = ci >> 3, j = ci & 7;
          int lane = q*16 + nn;
          whB[ks*1024 + lane*8 + j] = hi;
          whB[ks*1024 + 512 + lane*8 + j] = lo;
        }
      }
    } else {
      if (bid == 73 && t == 0) bar[0] = 0;  // reset post-kernel grid barrier
      int z = (bid - 73)*1024 + t;
      #pragma unroll
      for (int q = 0; q < 4; q++){
        int i = z + q*256;
        if (i < NLVL*NIMG*2048) ghist[i] = 0;
      }
    }
    return;
  }
  // xsplit part: chunk id = CB[l] + (n*32+cg)*HW + p ; 8 u16/chunk (ci)
  long id = (long)blockIdx.x*256 + t;
  if (blockIdx.x == 0 && t < 8) zp[t] = 0;  // 16B zero page
  if (id >= NCHUNK) return;
  int l = (id < d_CB[1]) ? 0 : (id < d_CB[2]) ? 1 : (id < d_CB[3]) ? 2 : (id < d_CB[4]) ? 3 : 4;
  long rem = id - d_CB[l];
  int HW = d_HW[l];
  int n = (int)(rem / (32*HW));
  int r2 = (int)(rem - (long)n*32*HW);
  int cg = r2 / HW;
  int p = r2 - cg*HW;
  const float* fm = (l==0)?f0:(l==1)?f1:(l==2)?f2:(l==3)?f3:f4;
  const float* gp = fm + ((size_t)(n*256 + cg*8))*HW + p;
  ushort8 hv, lv;
  #pragma unroll
  for (int j = 0; j < 8; j++){
    float v = gp[(size_t)j*HW];
    u16 hb, lb; f16_split(v, hb, lb);
    hv[j] = hb; lv[j] = lb;
  }
  *(ushort8*)&xh[id*8] = hv;
  *(ushort8*)&xl[id*8] = lv;
}

// ---------------- K1: conv3x3+relu + heads, 48-wide x 2-row tiles -----------
// R6 conv EXACT + fused pass-1 logit histogram. R7 (256,3)=spill disaster;
// R8 midhook=-47us — never again.
__global__ __launch_bounds__(256, 2) void conv_mfma(
    const float* __restrict__ f0, const float* __restrict__ f1,
    const float* __restrict__ f2, const float* __restrict__ f3,
    const float* __restrict__ f4,
    const u16* __restrict__ xh, const u16* __restrict__ xl,
    const u16* __restrict__ zp,
    const u16* __restrict__ wT, const u16* __restrict__ whB,
    const float* __restrict__ cb, const float* __restrict__ lb,
    const float* __restrict__ rb,
    float* __restrict__ lgb, float* __restrict__ rgb,
    u32* __restrict__ ghist, int use_dma)
{
  __shared__ __align__(16) u16 smem[26624];  // 53248 B: 2 x (xs_h 6656 + xs_l 6656)

  const int t = threadIdx.x;
  const int n = blockIdx.y;
  int bx = blockIdx.x;
  int l, rbk;
  if (bx < 700){ l = 0; rbk = bx; }
  else if (bx < 900){ l = 1; rbk = bx - 700; }
  else if (bx < 950){ l = 2; rbk = bx - 900; }
  else if (bx < 963){ l = 3; rbk = bx - 950; }
  else { l = 4; rbk = bx - 963; }
  const int H = d_H[l], W = d_W[l], tilesX = d_TX[l];
  const int ty2 = rbk / tilesX;                 // row-pair index
  const int x0 = (rbk - ty2*tilesX) * 48;
  const float* fm = (l==0) ? f0 : (l==1) ? f1 : (l==2) ? f2 : (l==3) ? f3 : f4;

  const int wave = t >> 6, lane = t & 63;
  const int quad = lane >> 4, l15 = lane & 15;
  const int HWp = H * W;
  const float* xin = fm + (size_t)n * 256 * HWp;

  f32x4 acc[2][3][4];
  #pragma unroll
  for (int r = 0; r < 2; r++)
    #pragma unroll
    for (int a = 0; a < 3; a++)
      #pragma unroll
      for (int b = 0; b < 4; b++) acc[r][a][b] = (f32x4){0.f,0.f,0.f,0.f};

  // MFMA tap loop: per tap, batch-load 4 B pairs, then 2 rows x 4 nt x 3 mt.
  // LDS A layout: [cg4][row4][xi52][8ci] (linear chunk index g*8).
  auto compute_cc = [&](int cc, int bufo){
    #pragma unroll
    for (int ky = 0; ky < 3; ky++){
      #pragma unroll
      for (int kx = 0; kx < 3; kx++){
        const u16* bt = wT + (size_t)((((ky*3+kx)*8 + cc)*16) + wave*4) * 1024 + lane*8;
        f16x8 Bh[4], Bl[4];
        #pragma unroll
        for (int nt = 0; nt < 4; nt++){
          Bh[nt] = *(const f16x8*)(bt + nt*1024);
          Bl[nt] = *(const f16x8*)(bt + nt*1024 + 512);
        }
        #pragma unroll
        for (int row = 0; row < 2; row++){
          int o0 = bufo + ((quad*4 + ky + row)*52 + (l15 + kx))*8;
          f16x8 Ah[3], Al[3];
          #pragma unroll
          for (int mt = 0; mt < 3; mt++){
            Ah[mt] = *(const f16x8*)&smem[o0 + mt*128];
            Al[mt] = *(const f16x8*)&smem[o0 + 6656 + mt*128];
          }
          #pragma unroll
          for (int nt = 0; nt < 4; nt++){
            #pragma unroll
            for (int mt = 0; mt < 3; mt++){
              acc[row][mt][nt] = __builtin_amdgcn_mfma_f32_16x16x32_f16(Ah[mt], Bh[nt], acc[row][mt][nt], 0,0,0);
              acc[row][mt][nt] = __builtin_amdgcn_mfma_f32_16x16x32_f16(Al[mt], Bh[nt], acc[row][mt][nt], 0,0,0);
              acc[row][mt][nt] = __builtin_amdgcn_mfma_f32_16x16x32_f16(Ah[mt], Bl[nt], acc[row][mt][nt], 0,0,0);
            }
          }
        }
      }
    }
  };

  if (use_dma){
    // per-slot DMA descriptors: wave issues slots k = wave + 4s (13 slots, exact)
    const u16* ph[4]; const u16* pl[4]; u32 pstep[4]; int dsth[4]; int kv[4];
    #pragma unroll
    for (int s = 0; s < 4; s++){
      int k = wave + s*4;
      kv[s] = (k < 13);
      int kk = kv[s] ? k : 0;
      int g = kk*64 + lane;              // chunk 0..831 (all real, 13x64=832)
      int cg = g / 208; int rem = g - cg*208;
      int r = rem / 52;  int xi = rem - r*52;
      int gy = ty2*2 - 1 + r, gx = x0 - 1 + xi;
      bool inb = (gy >= 0) && (gy < H) && (gx >= 0) && (gx < W);
      int gy2 = gy < 0 ? 0 : (gy >= H ? H-1 : gy);
      int gx2 = gx < 0 ? 0 : (gx >= W ? W-1 : gx);
      long off = d_XB[l] + (((long)(n*32 + cg))*HWp + (long)gy2*W + gx2)*8;
      ph[s] = inb ? (xh + off) : zp;
      pl[s] = inb ? (xl + off) : zp;
      pstep[s] = inb ? (u32)(32*HWp) : 0u;   // next cc: +4 channel-groups
      dsth[s] = kk*512;                      // u16 offset (k*1024 B)
    }
    auto stage = [&](int bufo){
      #pragma unroll
      for (int s = 0; s < 4; s++){
        if (kv[s]){
          dma16(ph[s], &smem[bufo + dsth[s]]);
          dma16(pl[s], &smem[bufo + 6656 + dsth[s]]);
          ph[s] += pstep[s]; pl[s] += pstep[s];
        }
      }
    };
    stage(0);
    __syncthreads();                        // drains DMA for cc=0
    for (int cc = 0; cc < 8; cc++){
      if (cc < 7) stage(((cc+1)&1)*13312);  // in flight during compute
      compute_cc(cc, (cc&1)*13312);
      __syncthreads();                      // drains next DMA + protects buf reuse
    }
  } else {
    // fallback (small ws): f32 staging + in-register split, single buffer
    for (int cc = 0; cc < 8; cc++){
      __syncthreads();
      #pragma unroll
      for (int it = 0; it < 4; it++){
        int G = t + it*256;
        if (G < 832){
          int cg = G / 208; int rem = G - cg*208;
          int r = rem / 52; int xi = rem - r*52;
          int gy = ty2*2 - 1 + r, gx = x0 - 1 + xi;
          bool inb = (gy >= 0) & (gy < H) & (gx >= 0) & (gx < W);
          const float* gp = xin + (size_t)(cc*32 + cg*8) * HWp
                          + (size_t)(gy < 0 ? 0 : gy) * W + (gx < 0 ? 0 : gx);
          ushort8 hv, lv;
          #pragma unroll
          for (int j = 0; j < 8; j++){
            float v = inb ? gp[(size_t)j * HWp] : 0.0f;
            u16 hb, lb2; f16_split(v, hb, lb2);
            hv[j] = hb; lv[j] = lb2;
          }
          int off = G*8;
          *(ushort8*)&smem[off] = hv;
          *(ushort8*)&smem[6656 + off] = lv;
        }
      }
      __syncthreads();
      compute_cc(cc, 0);
    }
    __syncthreads();
  }

  // fused pass-1 logit histogram: LDS bytes 34816..43008 — disjoint from
  // heads' hA_h/hA_l and sm_out; staging buffers dead after final cc barrier.
  u32* lhist = (u32*)(smem + 17408);
  for (int i = t; i < 2048; i += 256) lhist[i] = 0;

  // ---- heads per output row (unrolled, static acc index) ----
  u16* hA_h = smem;                // [64 pos][136]; rows 48..63 unused garbage
  u16* hA_l = smem + 8704;
  #pragma unroll
  for (int row = 0; row < 2; row++){
    const int ty = ty2*2 + row;
    const bool rowok = (ty < H);           // uniform per block
    if (rowok){
      f32x4 a2 = (f32x4){0.f,0.f,0.f,0.f};
      #pragma unroll
      for (int half = 0; half < 2; half++){
        if ((wave >> 1) == half){
          #pragma unroll
          for (int mt = 0; mt < 3; mt++){
            #pragma unroll
            for (int nt = 0; nt < 4; nt++){
              int col = (wave & 1)*64 + nt*16 + l15;   // local 0..127 in half
              float bias = cb[half*128 + col];
              #pragma unroll
              for (int r = 0; r < 4; r++){
                float h = fmaxf(acc[row][mt][nt][r] + bias, 0.0f);
                u16 hb, lb2; f16_split(h, hb, lb2);
                int pos = mt*16 + quad*4 + r;          // 0..47
                hA_h[pos*136 + col] = hb;
                hA_l[pos*136 + col] = lb2;
              }
            }
          }
        }
        __syncthreads();
        #pragma unroll
        for (int ks2 = 0; ks2 < 4; ks2++){
          int ks = half*4 + ks2;
          int ao = (wave*16 + l15)*136 + ks2*32 + quad*8;  // wave3: garbage rows
          f16x8 Ah = *(const f16x8*)&hA_h[ao];
          f16x8 Al = *(const f16x8*)&hA_l[ao];
          const u16* wb = whB + ks*1024 + lane*8;
          f16x8 Bh = *(const f16x8*)wb;
          f16x8 Bl = *(const f16x8*)(wb + 512);
          a2 = __builtin_amdgcn_mfma_f32_16x16x32_f16(Ah, Bh, a2, 0,0,0);
          a2 = __builtin_amdgcn_mfma_f32_16x16x32_f16(Al, Bh, a2, 0,0,0);
          a2 = __builtin_amdgcn_mfma_f32_16x16x32_f16(Ah, Bl, a2, 0,0,0);
        }
        __syncthreads();
      }

      // coalesced epilogue through LDS (rows 48..63 of sm_out never read)
      float* sm_out = (float*)smem;        // [64 pos][16]
      {
        int o = l15;
        float bias = (o < 3) ? lb[o] : ((o < 15) ? rb[o-3] : 0.0f);
        #pragma unroll
        for (int r = 0; r < 4; r++){
          int pos = wave*16 + quad*4 + r;
          sm_out[pos*16 + o] = a2[r] + bias;
        }
      }
      __syncthreads();
      {
        int P = W - x0; if (P > 48) P = 48;
        size_t pbase = (size_t)ty * W + x0;
        float* lg = lgb + d_LGOFF[l] + (size_t)n*HWp*3  + pbase*3;
        float* rg = rgb + d_RGOFF[l] + (size_t)n*HWp*12 + pbase*12;
        for (int j = t; j < P*3; j += 256){
          float v = sm_out[(j/3)*16 + (j%3)];
          lg[j] = v;
          atomicAdd(&lhist[okey(v) >> 21], 1u);
        }
        for (int j = t; j < P*12; j += 256) rg[j] = sm_out[(j/12)*16 + 3 + (j%12)];
      }
      __syncthreads();                     // before next row reuses smem
    }
  }

  // merge block-local histogram into the (l,n) global histogram
  {
    u32* gh = ghist + (size_t)(l*NIMG + n) * 2048;
    for (int i = t; i < 2048; i += 256){
      u32 h = lhist[i];
      if (h) atomicAdd(&gh[i], h);
    }
  }
}

// ---------------- K2: fused post chain — topk+sort+nms+merge, 10 blocks ----
// Phase A: per-(l,n) exact top-600 + decode (verbatim topk_decode).
// Phase B: per-image stable sort + rank lists (blocks 0,1; verbatim).
// Phase C: per-(n,l) NMS masks-in-LDS + greedy scan (verbatim, 1024 thr).
// Phase D: per-image cap-300 merge + output (blocks 0,1; verbatim).
// Grid barriers between phases; LDS is a 60032-B union (max phase = C).
__global__ __launch_bounds__(1024) void post(
    const float* __restrict__ lg, const float* __restrict__ rg,
    const float* __restrict__ pr0, const float* __restrict__ pr1,
    const float* __restrict__ pr2, const float* __restrict__ pr3,
    const float* __restrict__ pr4,
    const float* __restrict__ imsizes, const u32* __restrict__ ghist,
    float* __restrict__ cbox, float* __restrict__ cscore, u32* __restrict__ cvalid,
    float* __restrict__ sbox, float* __restrict__ sob,
    float* __restrict__ sarea, u32* __restrict__ svalid,
    u32* __restrict__ rlist, u32* __restrict__ kflag,
    float* __restrict__ out, u32* __restrict__ bar)
{
  __shared__ __align__(16) char smx[60032];
  int tid = threadIdx.x;
  int b = blockIdx.x;

  // ================= Phase A: topk_decode for (l,n) =================
  {
    u32* hist  = (u32*)smx;            // 8192 B
    u32* sscan = (u32*)(smx + 8192);   // 8192 B
    u64* sel   = (u64*)(smx + 16384);  // 8192 B
    u32* eqbuf = (u32*)(smx + 24576);  // 4096 B
    u32* scal  = (u32*)(smx + 28672);  // 32 B
    int l = b / NIMG;
    int n = b - l*NIMG;
    int HW = d_HW[l];
    int N = HW * 3;
    const float* lgl = lg + d_LGOFF[l] + (size_t)n * N;

    // pass 1: bits [31:21] — precomputed by conv_mfma's fused histogram
    {
      const u32* gh = ghist + (size_t)b * 2048;
      for (int i = tid; i < 2048; i += 1024){ u32 h = gh[i]; hist[i] = h; sscan[i] = h; }
    }
    __syncthreads();
    suffix_scan(sscan, 2048, tid);
    if (tid < 2048){
      u32 Si = sscan[tid], Sn = (tid+1 < 2048) ? sscan[tid+1] : 0u;
      if (Si >= LVTOP && Sn < LVTOP){ scal[0] = (u32)tid; scal[1] = Si - hist[tid]; }
    }
    { int i2 = tid + 1024;
      u32 Si = sscan[i2], Sn = (i2+1 < 2048) ? sscan[i2+1] : 0u;
      if (Si >= LVTOP && Sn < LVTOP){ scal[0] = (u32)i2; scal[1] = Si - hist[i2]; } }
    __syncthreads();
    u32 B1 = scal[0], base1 = scal[1];

    // pass 2: bits [20:10] within B1
    for (int i = tid; i < 2048; i += 1024) hist[i] = 0;
    __syncthreads();
    for (int i = tid; i < N; i += 1024){
      u32 k = okey(lgl[i]);
      if ((k >> 21) == B1) atomicAdd(&hist[(k >> 10) & 0x7FFu], 1u);
    }
    __syncthreads();
    for (int i = tid; i < 2048; i += 1024) sscan[i] = hist[i];
    __syncthreads();
    suffix_scan(sscan, 2048, tid);
    {
      u32 need = LVTOP - base1;
      if (tid < 2048){
        u32 Si = sscan[tid], Sn = (tid+1 < 2048) ? sscan[tid+1] : 0u;
        if (Si >= need && Sn < need){ scal[2] = (u32)tid; scal[3] = base1 + Si - hist[tid]; }
      }
      int i2 = tid + 1024;
      u32 Si = sscan[i2], Sn = (i2+1 < 2048) ? sscan[i2+1] : 0u;
      if (Si >= need && Sn < need){ scal[2] = (u32)i2; scal[3] = base1 + Si - hist[i2]; }
    }
    __syncthreads();
    u32 B2 = scal[2], base2 = scal[3];

    // pass 3: bits [9:0] within (B1,B2)
    for (int i = tid; i < 1024; i += 1024) hist[i] = 0;
    __syncthreads();
    u32 hi21 = (B1 << 11) | B2;
    for (int i = tid; i < N; i += 1024){
      u32 k = okey(lgl[i]);
      if ((k >> 10) == hi21) atomicAdd(&hist[k & 0x3FFu], 1u);
    }
    __syncthreads();
    for (int i = tid; i < 1024; i += 1024) sscan[i] = hist[i];
    __syncthreads();
    suffix_scan(sscan, 1024, tid);
    {
      u32 need = LVTOP - base2;
      if (tid < 1024){
        u32 Si = sscan[tid], Sn = (tid+1 < 1024) ? sscan[tid+1] : 0u;
        if (Si >= need && Sn < need){
          scal[4] = (hi21 << 10) | (u32)tid;
          scal[5] = base2 + Si - hist[tid];
        }
      }
    }
    if (tid == 0){ scal[6] = 0; scal[7] = 0; }
    __syncthreads();
    u32 T = scal[4], nAbove = scal[5], needEq = LVTOP - scal[5];

    for (int i = tid; i < 1024; i += 1024) sel[i] = 0;
    __syncthreads();
    for (int i = tid; i < N; i += 1024){
      u32 k = okey(lgl[i]);
      if (k > T){
        u32 p = atomicAdd(&scal[6], 1u);
        sel[p] = ((u64)k << 32) | (0xFFFFFFFFu - (u32)i);
      } else if (k == T){
        u32 p = atomicAdd(&scal[7], 1u);
        if (p < 1024) eqbuf[p] = (u32)i;
      }
    }
    __syncthreads();
    u32 cntE = scal[7];
    if (cntE > needEq){               // lowest-index ties (lax.top_k semantics)
      u32 m = cntE < 1024u ? cntE : 1024u;
      for (int i = tid; i < 1024; i += 1024) if ((u32)i >= m) eqbuf[i] = 0xFFFFFFFFu;
      __syncthreads();
      bitonic_asc32<1024,1024>(eqbuf, tid);
    }
    __syncthreads();
    if ((u32)tid < needEq)
      sel[nAbove + tid] = ((u64)T << 32) | (0xFFFFFFFFu - eqbuf[tid]);
    __syncthreads();
    // rank-by-count placement (600 real keys distinct -> unique ranks;
    // the 424 zeros all write identical 0 at rank 600 — benign).
    {
      u64 mykey = sel[tid];
      int rank = 0;
      for (int j = 0; j < 1024; j++) rank += (sel[j] > mykey) ? 1 : 0;
      __syncthreads();
      sel[rank] = mykey;
    }
    __syncthreads();

    // decode + clip + validity
    if (tid < LVTOP){
      u64 c = sel[tid];
      u32 i = 0xFFFFFFFFu - (u32)c;
      float val = lgl[i];
      float score = 1.0f / (1.0f + expf(-val));
      int pp = (int)i / 3, a = (int)i - pp*3;
      const float* pri;
      if (l == 0) pri = pr0; else if (l == 1) pri = pr1; else if (l == 2) pri = pr2;
      else if (l == 3) pri = pr3; else pri = pr4;
      pri += (size_t)i * 4;
      const float* rgp = rg + d_RGOFF[l] + ((size_t)n * HW + pp) * 12 + a * 4;
      float px0 = pri[0], py0 = pri[1], px1 = pri[2], py1 = pri[3];
      float pw = px1 - px0, ph = py1 - py0;
      float pcx = px0 + 0.5f*pw, pcy = py0 + 0.5f*ph;
      const float BC = (float)4.135166556742356;   // log(1000/16)
      float dx = rgp[0], dy = rgp[1];
      float dw = fminf(rgp[2], BC), dh = fminf(rgp[3], BC);
      float cx = dx*pw + pcx, cy = dy*ph + pcy;
      float bw = pw * expf(dw), bh = ph * expf(dh);
      float x1 = cx - 0.5f*bw, y1 = cy - 0.5f*bh;
      float x2 = cx + 0.5f*bw, y2 = cy + 0.5f*bh;
      float imh = imsizes[n*2+0], imw = imsizes[n*2+1];
      x1 = fminf(fmaxf(x1, 0.0f), imw);
      y1 = fminf(fmaxf(y1, 0.0f), imh);
      x2 = fminf(fmaxf(x2, 0.0f), imw);
      y2 = fminf(fmaxf(y2, 0.0f), imh);
      u32 valid = (score >= 0.0f) && ((x2 - x1) >= 1e-2f) && ((y2 - y1) >= 1e-2f);
      int ci = n*NCAND + l*LVTOP + tid;
      cbox[ci*4+0] = x1; cbox[ci*4+1] = y1; cbox[ci*4+2] = x2; cbox[ci*4+3] = y2;
      cscore[ci] = score; cvalid[ci] = valid;
    }
  }
  gsync(bar, FNB);

  // ================= Phase B: sort_cand for n = b (b < NIMG) =================
  if (b < NIMG){
    u64* a = (u64*)smx;                // 32768 B
    int n = b;
    for (int i = tid; i < 4096; i += 1024){
      if (i < NCAND){
        int ci = n*NCAND + i;
        float s = cvalid[ci] ? cscore[ci] : -1.0f;   // ref: where(valid, obj, -1)
        a[i] = ((u64)okey(s) << 32) | (0xFFFFFFFFu - (u32)i);
      } else a[i] = 0;
    }
    bitonic_desc64<4096,1024>(a, tid);
    int mylvl[3];
    #pragma unroll
    for (int q = 0; q < 3; q++){
      int r = tid + q*1024;
      mylvl[q] = 0;
      if (r < NCAND){
        u32 li = 0xFFFFFFFFu - (u32)a[r];
        int ci = n*NCAND + (int)li;
        float b0 = cbox[ci*4+0], b1 = cbox[ci*4+1], b2 = cbox[ci*4+2], b3 = cbox[ci*4+3];
        int lvl = (int)li / LVTOP;
        mylvl[q] = lvl;
        float off = (float)(n*10 + lvl) * 4096.0f;   // fp32 batched_nms offset
        int so = n*NCAND + r;
        sbox[so*4+0]=b0; sbox[so*4+1]=b1; sbox[so*4+2]=b2; sbox[so*4+3]=b3;
        float o0=b0+off, o1=b1+off, o2=b2+off, o3=b3+off;
        sob[so*4+0]=o0; sob[so*4+1]=o1; sob[so*4+2]=o2; sob[so*4+3]=o3;
        sarea[so] = (o2-o0)*(o3-o1);
        svalid[so] = cvalid[ci];
      }
    }
    __syncthreads();
    // per-level stable position via one u64 multi-field inclusive scan
    #pragma unroll
    for (int q = 0; q < 3; q++){
      int r = tid + q*1024;
      a[r] = (r < NCAND) ? (1ull << (12*mylvl[q])) : 0ull;
    }
    a[tid + 3072] = 0ull;
    __syncthreads();
    for (int off = 1; off < 4096; off <<= 1){
      u64 v[4];
      #pragma unroll
      for (int q = 0; q < 4; q++){
        int i = tid + q*1024;
        v[q] = a[i] + ((i >= off) ? a[i-off] : 0ull);
      }
      __syncthreads();
      #pragma unroll
      for (int q = 0; q < 4; q++) a[tid + q*1024] = v[q];
      __syncthreads();
    }
    #pragma unroll
    for (int q = 0; q < 3; q++){
      int r = tid + q*1024;
      if (r < NCAND){
        int lv = mylvl[q];
        int pos = (int)((a[r] >> (12*lv)) & 0xFFFull) - 1;
        rlist[(n*NLVL + lv)*LVTOP + pos] = (u32)r;
        kflag[n*NCAND + r] = 0u;
      }
    }
  }
  gsync(bar, 2*FNB);

  // ================= Phase C: NMS for nl = b =================
  {
    float* bxx = (float*)smx;          // 12000 B
    u64* pm = (u64*)(smx + 12032);     // 48000 B (8-aligned)
    int nl = b, n = nl / NLVL;
    // stage boxes in rlist order
    for (int i = tid; i < LVTOP; i += 1024){
      int so = n*NCAND + (int)rlist[nl*LVTOP + i];
      bxx[i*5+0]=sob[so*4+0]; bxx[i*5+1]=sob[so*4+1];
      bxx[i*5+2]=sob[so*4+2]; bxx[i*5+3]=sob[so*4+3];
      bxx[i*5+4]=sarea[so];
    }
    __syncthreads();
    // mask build
    for (int i = tid; i < LVTOP; i += 1024){
      int so = n*NCAND + (int)rlist[nl*LVTOP + i];
      bool act = svalid[so] != 0;
      float oi0=bxx[i*5+0], oi1=bxx[i*5+1], oi2=bxx[i*5+2], oi3=bxx[i*5+3], ai=bxx[i*5+4];
      for (int w = 0; w < 10; w++){
        u64 bits = 0;
        if (act){
          int jj0 = (i >= w*64) ? (i - w*64 + 1) : 0;
          int jjend = (LVTOP - w*64 < 64) ? (LVTOP - w*64) : 64;
          for (int jj = jj0; jj < jjend; jj++){
            int j = w*64 + jj;
            float oj0=bxx[j*5+0], oj1=bxx[j*5+1], oj2=bxx[j*5+2], oj3=bxx[j*5+3], aj=bxx[j*5+4];
            float ltx = fmaxf(oi0, oj0), lty = fmaxf(oi1, oj1);
            float rbx = fminf(oi2, oj2), rby = fminf(oi3, oj3);
            float wx = fmaxf(rbx - ltx, 0.0f), wy = fmaxf(rby - lty, 0.0f);
            float inter = wx * wy;
            float iou = inter / ((ai + aj) - inter);
            if (iou > 0.7f) bits |= (1ull << jj);
          }
        }
        pm[i*10 + w] = bits;
      }
    }
    __syncthreads();
    if (tid < 64){
      u64 vw = 0, remv = 0;
      for (int c = 0; c < 10; c++){
        int i = c*64 + tid;
        int pred = 0;
        if (i < LVTOP) pred = svalid[n*NCAND + (int)rlist[nl*LVTOP + i]] != 0;
        u64 bl = __ballot(pred);
        if (tid == c) vw = bl;
      }
      for (int w = 0; w < 10; w++){
        u64 act = shfl64(vw, w) & ~shfl64(remv, w);
        while (act){
          int bpos = __builtin_ctzll(act);
          int i = w*64 + bpos;
          if (tid == 0) kflag[n*NCAND + (int)rlist[nl*LVTOP + i]] = 1u;
          u64 m = (tid < 10) ? pm[i*10 + tid] : 0ull;
          u64 mw = pm[i*10 + w];         // broadcast (same addr all lanes)
          remv |= m;
          act &= ~(1ull << bpos);
          act &= ~mw;
        }
      }
    }
  }
  gsync(bar, 3*FNB);

  // ================= Phase D: merge_out for n = b (b < NIMG) =================
  if (b < NIMG){
    u32* ps = (u32*)smx;               // 16384 B
    int n = b;
    u32 f[4];
    #pragma unroll
    for (int q = 0; q < 4; q++){
      int i = tid + q*1024;
      f[q] = (i < NCAND) ? kflag[n*NCAND + i] : 0u;
      ps[i] = f[q];
    }
    __syncthreads();
    for (int off = 1; off < 4096; off <<= 1){
      u32 v[4];
      #pragma unroll
      for (int q = 0; q < 4; q++){
        int i = tid + q*1024;
        v[q] = ps[i] + ((i >= off) ? ps[i-off] : 0u);
      }
      __syncthreads();
      #pragma unroll
      for (int q = 0; q < 4; q++) ps[tid + q*1024] = v[q];
      __syncthreads();
    }
    #pragma unroll
    for (int q = 0; q < 4; q++){
      int i = tid + q*1024;
      if (i < NCAND && f[q] && ps[i] <= IMTOP){
        int slot = n*IMTOP + (int)ps[i] - 1;
        int so = n*NCAND + i;
        out[slot*4+0] = sbox[so*4+0]; out[slot*4+1] = sbox[so*4+1];
        out[slot*4+2] = sbox[so*4+2]; out[slot*4+3] = sbox[so*4+3];
      }
    }
    u32 kept = ps[NCAND-1]; if (kept > IMTOP) kept = IMTOP;
    for (int j = tid; j < IMTOP; j += 1024){
      int slot = n*IMTOP + j;
      if ((u32)j >= kept){
        out[slot*4+0]=0; out[slot*4+1]=0; out[slot*4+2]=0; out[slot*4+3]=0;
      }
      out[2400 + slot] = (float)n;
      out[3000 + slot] = ((u32)j < kept) ? 1.0f : 0.0f;
    }
  }
}

extern "C" void kernel_launch(void* const* d_in, const int* in_sizes, int n_in,
                              void* d_out, int out_size, void* d_ws, size_t ws_size,
                              hipStream_t stream)
{
  const float* fmap[5]   = {(const float*)d_in[0], (const float*)d_in[2], (const float*)d_in[4],
                            (const float*)d_in[6], (const float*)d_in[8]};
  const float* priors[5] = {(const float*)d_in[1], (const float*)d_in[3], (const float*)d_in[5],
                            (const float*)d_in[7], (const float*)d_in[9]};
  const float* imsz   = (const float*)d_in[10];
  const float* conv_w = (const float*)d_in[11];
  const float* conv_b = (const float*)d_in[12];
  const float* log_w  = (const float*)d_in[13];
  const float* log_b  = (const float*)d_in[14];
  const float* reg_w  = (const float*)d_in[15];
  const float* reg_b  = (const float*)d_in[16];

  char* base = (char*)d_ws;
  float* lg     = (float*)(base + 0);          // 1943928 B
  float* rg     = (float*)(base + 1943928);    // 7775712 B
  float* cscore = (float*)(base + 9719640);
  float* cbox   = (float*)(base + 9743640);
  u32*   cvalid = (u32*)  (base + 9839640);
  float* sbox   = (float*)(base + 9863640);
  float* sob    = (float*)(base + 9959640);
  float* sarea  = (float*)(base + 10055640);
  u32*   svalid = (u32*)  (base + 10079640);
  u32*   rlist  = (u32*)  (base + 10103640);   // 24000 B
  u32*   kflag  = (u32*)  (base + 10127640);   // 24000 B
  u32*   ghist  = (u32*)  (base + 10151648);   // 81920 B (10 x 2048 u32)
  u32*   bar    = (u32*)  (base + 10233568);   // 4 B grid barrier (zeroed in prep)
  u16*   wT     = (u16*)  (base + 10631648);   // 2359296 B
  u16*   whB    = (u16*)  (base + 12990944);   // 16384 B
  u16*   zp     = (u16*)  (base + 13007328);   // 16 B zero page
  u16*   xh     = (u16*)  (base + 13007344);   // 82940928 B
  u16*   xl     = (u16*)  (base + 95948272);   // 82940928 B -> 178889200

  int use_dma = (ws_size >= WS_NEED) ? 1 : 0;
  int xsb = use_dma ? NXB : 0;

  prep<<<xsb + 93, 256, 0, stream>>>(
      fmap[0], fmap[1], fmap[2], fmap[3], fmap[4], xh, xl, zp,
      conv_w, log_w, reg_w, wT, whB, ghist, bar, xsb);

  conv_mfma<<<dim3(970, NIMG), 256, 0, stream>>>(
      fmap[0], fmap[1], fmap[2], fmap[3], fmap[4],
      xh, xl, zp, wT, whB, conv_b, log_b, reg_b, lg, rg, ghist, use_dma);

  post<<<FNB, 1024, 0, stream>>>(lg, rg,
      priors[0], priors[1], priors[2], priors[3], priors[4],
      imsz, ghist, cbox, cscore, cvalid,
      sbox, sob, sarea, svalid, rlist, kflag, (float*)d_out, bar);
}